// Round 4
// baseline (293.315 us; speedup 1.0000x reference)
//
#include <hip/hip_runtime.h>
#include <cstddef>

// Problem constants
#define P_TOTAL 32768            // keys (32 images x 32 x 32)
#define Q_TOTAL 4096             // queries (4 x 32 x 32)
#define NSPLIT 64                // key splits
#define KPS 512                  // keys per split
#define TILES 32                 // 16-key MFMA tiles per split
#define QPERWG 256               // queries per workgroup (4 waves x 64)
#define NQG (Q_TOTAL / QPERWG)   // 16 query groups
#define GRID (NSPLIT * NQG)      // 1024 workgroups
#define FINW 16                  // finisher workgroups (combine)
#define FQ (Q_TOTAL / FINW)      // 256 queries per finisher

typedef _Float16 half8 __attribute__((ext_vector_type(8)));
typedef _Float16 half4v __attribute__((ext_vector_type(4)));
typedef float floatx4 __attribute__((ext_vector_type(4)));

__device__ __forceinline__ float fexp2(float x) {
#if defined(__has_builtin) && __has_builtin(__builtin_amdgcn_exp2f)
    return __builtin_amdgcn_exp2f(x);
#else
    return exp2f(x);
#endif
}

// ---------------------------------------------------------------------------
// Fully fused kernel. wg = (split, qgroup).
//  Phase 1: build this split's 512 keys directly into LDS (f16 rows of 64 B:
//           27 scaled vals, bias, 3 f16 centers, 0; XOR-swizzled 16B chunks).
//           A-fragments built in registers straight from x (circular pad).
//  Phase 2: two-pass flash scoring (max pass, then exp2 pass with -m folded
//           into the MFMA C operand); butterfly over 16 col lanes; col==0
//           writes per-split partials.
//  Phase 3: release fence + ticket; last FINW wgs spin, acquire, and do the
//           online 64-split combine + output write.
// ---------------------------------------------------------------------------
__global__ __launch_bounds__(256, 4) void fused_k(
    const float* __restrict__ x, const float* __restrict__ images,
    const float* __restrict__ mu_sched, const float* __restrict__ sigma_sched,
    const int* __restrict__ tptr,
    float* __restrict__ partials, int* __restrict__ ticket,
    float* __restrict__ out)
{
    __shared__ char lds[KPS * 64];   // 32768 B
    int tid = threadIdx.x;
    int split = blockIdx.x >> 4;     // 0..63
    int qg    = blockIdx.x & 15;     // 0..15

    int t = tptr[0];
    float mu = mu_sched[t], sg = sigma_sched[t];
    const float LOG2E = 1.4426950408889634f;
    float inv2s2 = 1.0f / (2.0f * sg * sg);
    float s1     = 2.0f * mu * inv2s2 * LOG2E;   // key value scale
    float bscale = -mu * mu * inv2s2 * LOG2E;    // pnorm bias scale
    float inv_s2 = 1.0f / (sg * sg);

    // ---- Phase 1a: build 512 keys of this split into LDS (2 per thread) ----
    #pragma unroll
    for (int kk = 0; kk < 2; kk++) {
        int r = tid + kk * 256;                  // LDS row 0..511
        int p = split * KPS + r;                 // global key id
        int n = p >> 10, rem = p & 1023, i = rem >> 5, j = rem & 31;
        const float* img = images + (size_t)n * 3072;
        _Float16 hrow[32];
        float pnorm = 0.f, c0 = 0.f, c1 = 0.f, c2 = 0.f;
        #pragma unroll
        for (int c = 0; c < 3; c++)
          #pragma unroll
          for (int di = 0; di < 3; di++)
            #pragma unroll
            for (int dj = 0; dj < 3; dj++) {
                int ii = i + di - 1, jj = j + dj - 1;
                float val = 0.f;
                if (ii >= 0 && ii < 32 && jj >= 0 && jj < 32)
                    val = img[c * 1024 + ii * 32 + jj];
                hrow[c * 9 + di * 3 + dj] = (_Float16)(val * s1);
                pnorm = fmaf(val, val, pnorm);
                if (di == 1 && dj == 1) { if (c == 0) c0 = val; else if (c == 1) c1 = val; else c2 = val; }
            }
        hrow[27] = (_Float16)(pnorm * bscale);
        hrow[28] = (_Float16)c0; hrow[29] = (_Float16)c1;
        hrow[30] = (_Float16)c2; hrow[31] = (_Float16)0.f;
        int sw = (r >> 1) & 3;                   // chunk XOR swizzle
        float4* src4 = (float4*)hrow;
        #pragma unroll
        for (int c = 0; c < 4; c++)
            *(float4*)(lds + r * 64 + ((c ^ sw) << 4)) = src4[c];
    }

    // ---- Phase 1b: A-fragments in registers, straight from x ----
    int lane = tid & 63, wid = tid >> 6;
    int col  = lane & 15, quad = lane >> 4;
    int qbase = qg * QPERWG + wid * 64;

    half8 af[4];
    #pragma unroll
    for (int f = 0; f < 4; f++) {
        int q = qbase + f * 16 + col;
        int b = q >> 10, qr = q & 1023, h = qr >> 5, w = qr & 31;
        const float* xb = x + (size_t)b * 3072;
        half8 v;
        #pragma unroll
        for (int jj = 0; jj < 8; jj++) {
            int u = quad * 8 + jj;
            float val;
            if (u < 27) {
                int c = u / 9, rm = u % 9, di = rm / 3, dj = rm % 3;
                val = xb[c * 1024 + ((h + di + 31) & 31) * 32 + ((w + dj + 31) & 31)];
            } else {
                val = (u == 27) ? 1.0f : 0.0f;
            }
            v[jj] = (_Float16)val;
        }
        af[f] = v;
    }
    __syncthreads();

    int swc = (col >> 1) & 3;
    const char* bbase = lds + col * 64 + ((quad ^ swc) << 4);
    const char* cbase = lds + col * 64 + ((3 ^ swc) << 4) + 8;   // halves 28..31

    // ---- Pass 1: per-row max ----
    floatx4 mv[4];
    #pragma unroll
    for (int f = 0; f < 4; f++) mv[f] = (floatx4){-3e38f, -3e38f, -3e38f, -3e38f};
    {
        #pragma unroll 4
        for (int tile = 0; tile < TILES; tile++) {
            half8 b = *(const half8*)(bbase + tile * 1024);
            #pragma unroll
            for (int f = 0; f < 4; f++) {
                floatx4 a = __builtin_amdgcn_mfma_f32_16x16x32_f16(
                    af[f], b, (floatx4){0.f, 0.f, 0.f, 0.f}, 0, 0, 0);
                #pragma unroll
                for (int r = 0; r < 4; r++) mv[f][r] = fmaxf(mv[f][r], a[r]);
            }
        }
    }
    #pragma unroll
    for (int sh = 1; sh < 16; sh <<= 1)
        #pragma unroll
        for (int f = 0; f < 4; f++)
            #pragma unroll
            for (int r = 0; r < 4; r++)
                mv[f][r] = fmaxf(mv[f][r], __shfl_xor(mv[f][r], sh, 64));

    floatx4 nm[4];
    #pragma unroll
    for (int f = 0; f < 4; f++) nm[f] = -mv[f];

    // ---- Pass 2: exp2 + accumulate (max folded into MFMA C operand) ----
    floatx4 sv[4], w0[4], w1[4], w2[4];
    #pragma unroll
    for (int f = 0; f < 4; f++) {
        sv[f] = (floatx4){0.f, 0.f, 0.f, 0.f};
        w0[f] = sv[f]; w1[f] = sv[f]; w2[f] = sv[f];
    }
    {
        #pragma unroll 2
        for (int tile = 0; tile < TILES; tile++) {
            half8 b = *(const half8*)(bbase + tile * 1024);
            half4v ch = *(const half4v*)(cbase + tile * 1024);
            float c0 = (float)ch[0], c1 = (float)ch[1], c2 = (float)ch[2];
            #pragma unroll
            for (int f = 0; f < 4; f++) {
                floatx4 a = __builtin_amdgcn_mfma_f32_16x16x32_f16(af[f], b, nm[f], 0, 0, 0);
                #pragma unroll
                for (int r = 0; r < 4; r++) {
                    float e = fexp2(a[r]);
                    sv[f][r] += e;
                    w0[f][r] = fmaf(e, c0, w0[f][r]);
                    w1[f][r] = fmaf(e, c1, w1[f][r]);
                    w2[f][r] = fmaf(e, c2, w2[f][r]);
                }
            }
        }
    }
    #pragma unroll
    for (int sh = 1; sh < 16; sh <<= 1)
        #pragma unroll
        for (int f = 0; f < 4; f++)
            #pragma unroll
            for (int r = 0; r < 4; r++) {
                sv[f][r] += __shfl_xor(sv[f][r], sh, 64);
                w0[f][r] += __shfl_xor(w0[f][r], sh, 64);
                w1[f][r] += __shfl_xor(w1[f][r], sh, 64);
                w2[f][r] += __shfl_xor(w2[f][r], sh, 64);
            }

    if (col == 0) {
        #pragma unroll
        for (int f = 0; f < 4; f++)
            #pragma unroll
            for (int r = 0; r < 4; r++) {
                int q = qbase + f * 16 + quad * 4 + r;
                float* pp = partials + ((size_t)split * Q_TOTAL + q) * 8;
                *(float4*)pp = make_float4(mv[f][r], sv[f][r], w0[f][r], w1[f][r]);
                pp[4] = w2[f][r];
            }
    }

    // ---- Phase 3: release + ticket; last FINW wgs combine ----
    __threadfence();             // device-scope release (L2 writeback)
    __syncthreads();
    if (tid == 0)
        *(int*)lds = atomicAdd(ticket, 1);
    __syncthreads();
    int old = *(const int*)lds;
    if (old < GRID - FINW) return;

    if (tid == 0) {
        while (__hip_atomic_load(ticket, __ATOMIC_RELAXED, __HIP_MEMORY_SCOPE_AGENT) < GRID)
            __builtin_amdgcn_s_sleep(8);
    }
    __syncthreads();
    __threadfence();             // device-scope acquire (cache invalidate)

    int fid = old - (GRID - FINW);       // 0..FINW-1
    int q = fid * FQ + tid;              // this thread's query
    float M = -3e38f, S = 0.f, W0 = 0.f, W1 = 0.f, W2 = 0.f;
    for (int sp = 0; sp < NSPLIT; sp++) {
        const float* pp = partials + ((size_t)sp * Q_TOTAL + q) * 8;
        float4 a = *(const float4*)pp;
        float w2v = pp[4];
        float mnew = fmaxf(M, a.x);
        float sco = fexp2(M - mnew);
        float scn = fexp2(a.x - mnew);
        S  = fmaf(S,  sco, a.y * scn);
        W0 = fmaf(W0, sco, a.z * scn);
        W1 = fmaf(W1, sco, a.w * scn);
        W2 = fmaf(W2, sco, w2v * scn);
        M = mnew;
    }
    float invS = 1.0f / S;
    int b = q >> 10, rem = q & 1023;
    #pragma unroll
    for (int c = 0; c < 3; c++) {
        float Wc = (c == 0) ? W0 : (c == 1 ? W1 : W2);
        float xc = x[(size_t)b * 3072 + c * 1024 + rem];
        out[(size_t)b * 3072 + c * 1024 + rem] = -(xc - mu * Wc * invS) * inv_s2;
    }
}

extern "C" void kernel_launch(void* const* d_in, const int* in_sizes, int n_in,
                              void* d_out, int out_size, void* d_ws, size_t ws_size,
                              hipStream_t stream) {
    const float* x      = (const float*)d_in[0];
    const float* images = (const float*)d_in[1];
    const float* mu_s   = (const float*)d_in[2];
    const float* sg_s   = (const float*)d_in[3];
    const int*   tptr   = (const int*)d_in[4];
    float* out = (float*)d_out;

    float* partials = (float*)d_ws;                                    // 8 MB
    int*   ticket   = (int*)((char*)d_ws + (size_t)NSPLIT * Q_TOTAL * 8 * 4);

    hipMemsetAsync(ticket, 0, 4, stream);
    fused_k<<<GRID, 256, 0, stream>>>(
        x, images, mu_s, sg_s, tptr, partials, ticket, out);
}

// Round 5
// 125.635 us; speedup vs baseline: 2.3347x; 2.3347x over previous
//
#include <hip/hip_runtime.h>
#include <cstddef>

// Problem constants
#define P_TOTAL 32768            // keys (32 images x 32 x 32)
#define Q_TOTAL 4096             // queries (4 x 32 x 32)
#define NSPLIT 64                // key splits
#define KPS 512                  // keys per split
#define TILES 32                 // 16-key MFMA tiles per split
#define QPERWG 256               // queries per workgroup (4 waves x 64)
#define NQG (Q_TOTAL / QPERWG)   // 16 query groups
#define GRID (NSPLIT * NQG)      // 1024 workgroups

typedef _Float16 half8 __attribute__((ext_vector_type(8)));
typedef _Float16 half4v __attribute__((ext_vector_type(4)));
typedef float floatx4 __attribute__((ext_vector_type(4)));

__device__ __forceinline__ float fexp2(float x) {
#if defined(__has_builtin) && __has_builtin(__builtin_amdgcn_exp2f)
    return __builtin_amdgcn_exp2f(x);
#else
    return exp2f(x);
#endif
}

// ---------------------------------------------------------------------------
// Kernel 1: q16[Q][32] f16 query rows (27 patch vals, 1.0 bias-mate, zeros).
// ---------------------------------------------------------------------------
__global__ __launch_bounds__(256) void qbuild_k(
    const float* __restrict__ x, _Float16* __restrict__ q16)
{
    int q = blockIdx.x * 256 + threadIdx.x;   // 0..4095
    int b = q >> 10, rem = q & 1023, h = rem >> 5, w = rem & 31;
    const float* xb = x + (size_t)b * 3072;
    _Float16 row[32];
    #pragma unroll
    for (int c = 0; c < 3; c++)
      #pragma unroll
      for (int di = 0; di < 3; di++)
        #pragma unroll
        for (int dj = 0; dj < 3; dj++)
            row[c * 9 + di * 3 + dj] =
                (_Float16)xb[c * 1024 + ((h + di + 31) & 31) * 32 + ((w + dj + 31) & 31)];
    row[27] = (_Float16)1.0f;
    row[28] = (_Float16)0.f; row[29] = (_Float16)0.f;
    row[30] = (_Float16)0.f; row[31] = (_Float16)0.f;
    _Float16* qp = q16 + (size_t)q * 32;
    #pragma unroll
    for (int u = 0; u < 4; u++) ((float4*)qp)[u] = ((float4*)row)[u];
}

// ---------------------------------------------------------------------------
// Kernel 2: fused key-build + flash scorer. wg = (split, qgroup).
// Keys built directly into 32 KB LDS (64-B f16 rows: 27 scaled vals, bias,
// 3 f16 centers, 0; 16B chunks XOR-swizzled by (row>>1)&3 -> conflict-minimal
// ds_read_b128). Pass 1: per-row max. Pass 2: exp2 with -m folded into the
// MFMA C operand + weighted-center accumulate. Butterfly over 16 col lanes.
// No launch-bounds min-waves: accumulators need ~100 VGPRs (R4 spilled at 64).
// ---------------------------------------------------------------------------
__global__ __launch_bounds__(256) void score_k(
    const _Float16* __restrict__ q16, const float* __restrict__ images,
    const float* __restrict__ mu_sched, const float* __restrict__ sigma_sched,
    const int* __restrict__ tptr, float* __restrict__ partials)
{
    __shared__ char lds[KPS * 64];   // 32768 B
    int tid = threadIdx.x;
    int split = blockIdx.x >> 4;     // 0..63
    int qg    = blockIdx.x & 15;     // 0..15

    int t = tptr[0];
    float mu = mu_sched[t], sg = sigma_sched[t];
    const float LOG2E = 1.4426950408889634f;
    float inv2s2 = 1.0f / (2.0f * sg * sg);
    float s1     = 2.0f * mu * inv2s2 * LOG2E;   // key value scale
    float bscale = -mu * mu * inv2s2 * LOG2E;    // pnorm bias scale

    // ---- Phase 1: build this split's 512 keys into LDS (2 per thread) ----
    #pragma unroll
    for (int kk = 0; kk < 2; kk++) {
        int r = tid + kk * 256;                  // LDS row 0..511
        int p = split * KPS + r;                 // global key id
        int n = p >> 10, rem = p & 1023, i = rem >> 5, j = rem & 31;
        const float* img = images + (size_t)n * 3072;
        _Float16 hrow[32];
        float pnorm = 0.f, c0 = 0.f, c1 = 0.f, c2 = 0.f;
        #pragma unroll
        for (int c = 0; c < 3; c++)
          #pragma unroll
          for (int di = 0; di < 3; di++)
            #pragma unroll
            for (int dj = 0; dj < 3; dj++) {
                int ii = i + di - 1, jj = j + dj - 1;
                float val = 0.f;
                if (ii >= 0 && ii < 32 && jj >= 0 && jj < 32)
                    val = img[c * 1024 + ii * 32 + jj];
                hrow[c * 9 + di * 3 + dj] = (_Float16)(val * s1);
                pnorm = fmaf(val, val, pnorm);
                if (di == 1 && dj == 1) { if (c == 0) c0 = val; else if (c == 1) c1 = val; else c2 = val; }
            }
        hrow[27] = (_Float16)(pnorm * bscale);
        hrow[28] = (_Float16)c0; hrow[29] = (_Float16)c1;
        hrow[30] = (_Float16)c2; hrow[31] = (_Float16)0.f;
        int sw = (r >> 1) & 3;                   // chunk XOR swizzle
        float4* src4 = (float4*)hrow;
        #pragma unroll
        for (int c = 0; c < 4; c++)
            *(float4*)(lds + r * 64 + ((c ^ sw) << 4)) = src4[c];
    }

    // ---- A-fragments from q16 (global, L2-hot, one b128 per frag) ----
    int lane = tid & 63, wid = tid >> 6;
    int col  = lane & 15, quad = lane >> 4;
    int qbase = qg * QPERWG + wid * 64;

    half8 af[4];
    #pragma unroll
    for (int f = 0; f < 4; f++)
        af[f] = *(const half8*)(q16 + (size_t)(qbase + f * 16 + col) * 32 + quad * 8);
    __syncthreads();

    int swc = (col >> 1) & 3;
    const char* bbase = lds + col * 64 + ((quad ^ swc) << 4);
    const char* cbase = lds + col * 64 + ((3 ^ swc) << 4) + 8;   // halves 28..31

    // ---- Pass 1: per-row max ----
    floatx4 mv[4];
    #pragma unroll
    for (int f = 0; f < 4; f++) mv[f] = (floatx4){-3e38f, -3e38f, -3e38f, -3e38f};
    {
        #pragma unroll 4
        for (int tile = 0; tile < TILES; tile++) {
            half8 b = *(const half8*)(bbase + tile * 1024);
            #pragma unroll
            for (int f = 0; f < 4; f++) {
                floatx4 a = __builtin_amdgcn_mfma_f32_16x16x32_f16(
                    af[f], b, (floatx4){0.f, 0.f, 0.f, 0.f}, 0, 0, 0);
                #pragma unroll
                for (int r = 0; r < 4; r++) mv[f][r] = fmaxf(mv[f][r], a[r]);
            }
        }
    }
    #pragma unroll
    for (int sh = 1; sh < 16; sh <<= 1)
        #pragma unroll
        for (int f = 0; f < 4; f++)
            #pragma unroll
            for (int r = 0; r < 4; r++)
                mv[f][r] = fmaxf(mv[f][r], __shfl_xor(mv[f][r], sh, 64));

    floatx4 nm[4];
    #pragma unroll
    for (int f = 0; f < 4; f++) nm[f] = -mv[f];

    // ---- Pass 2: exp2 + accumulate (max folded into MFMA C operand) ----
    floatx4 sv[4], w0[4], w1[4], w2[4];
    #pragma unroll
    for (int f = 0; f < 4; f++) {
        sv[f] = (floatx4){0.f, 0.f, 0.f, 0.f};
        w0[f] = sv[f]; w1[f] = sv[f]; w2[f] = sv[f];
    }
    {
        #pragma unroll 2
        for (int tile = 0; tile < TILES; tile++) {
            half8 b = *(const half8*)(bbase + tile * 1024);
            half4v ch = *(const half4v*)(cbase + tile * 1024);
            float c0 = (float)ch[0], c1 = (float)ch[1], c2 = (float)ch[2];
            #pragma unroll
            for (int f = 0; f < 4; f++) {
                floatx4 a = __builtin_amdgcn_mfma_f32_16x16x32_f16(af[f], b, nm[f], 0, 0, 0);
                #pragma unroll
                for (int r = 0; r < 4; r++) {
                    float e = fexp2(a[r]);
                    sv[f][r] += e;
                    w0[f][r] = fmaf(e, c0, w0[f][r]);
                    w1[f][r] = fmaf(e, c1, w1[f][r]);
                    w2[f][r] = fmaf(e, c2, w2[f][r]);
                }
            }
        }
    }
    #pragma unroll
    for (int sh = 1; sh < 16; sh <<= 1)
        #pragma unroll
        for (int f = 0; f < 4; f++)
            #pragma unroll
            for (int r = 0; r < 4; r++) {
                sv[f][r] += __shfl_xor(sv[f][r], sh, 64);
                w0[f][r] += __shfl_xor(w0[f][r], sh, 64);
                w1[f][r] += __shfl_xor(w1[f][r], sh, 64);
                w2[f][r] += __shfl_xor(w2[f][r], sh, 64);
            }

    if (col == 0) {
        #pragma unroll
        for (int f = 0; f < 4; f++)
            #pragma unroll
            for (int r = 0; r < 4; r++) {
                int q = qbase + f * 16 + quad * 4 + r;
                float* pp = partials + ((size_t)split * Q_TOTAL + q) * 8;
                *(float4*)pp = make_float4(mv[f][r], sv[f][r], w0[f][r], w1[f][r]);
                pp[4] = w2[f][r];
            }
    }
}

// ---------------------------------------------------------------------------
// Kernel 3: merge NSPLIT partials per query (online), write output.
// ---------------------------------------------------------------------------
__global__ __launch_bounds__(256) void combine_k(
    const float* __restrict__ x, const float* __restrict__ partials,
    const float* __restrict__ mu_sched, const float* __restrict__ sigma_sched,
    const int* __restrict__ tptr, float* __restrict__ out)
{
    int q = blockIdx.x * 256 + threadIdx.x;   // 0..4095
    int t = tptr[0];
    float mu = mu_sched[t], sg = sigma_sched[t];
    float inv_s2 = 1.0f / (sg * sg);

    float M = -3e38f, S = 0.f, W0 = 0.f, W1 = 0.f, W2 = 0.f;
    for (int sp = 0; sp < NSPLIT; sp++) {
        const float* pp = partials + ((size_t)sp * Q_TOTAL + q) * 8;
        float4 a = *(const float4*)pp;
        float w2v = pp[4];
        float mnew = fmaxf(M, a.x);
        float sco = fexp2(M - mnew);
        float scn = fexp2(a.x - mnew);
        S  = fmaf(S,  sco, a.y * scn);
        W0 = fmaf(W0, sco, a.z * scn);
        W1 = fmaf(W1, sco, a.w * scn);
        W2 = fmaf(W2, sco, w2v * scn);
        M = mnew;
    }
    float invS = 1.0f / S;
    int b = q >> 10, rem = q & 1023;
    #pragma unroll
    for (int c = 0; c < 3; c++) {
        float Wc = (c == 0) ? W0 : (c == 1 ? W1 : W2);
        float xc = x[(size_t)b * 3072 + c * 1024 + rem];
        out[(size_t)b * 3072 + c * 1024 + rem] = -(xc - mu * Wc * invS) * inv_s2;
    }
}

extern "C" void kernel_launch(void* const* d_in, const int* in_sizes, int n_in,
                              void* d_out, int out_size, void* d_ws, size_t ws_size,
                              hipStream_t stream) {
    const float* x      = (const float*)d_in[0];
    const float* images = (const float*)d_in[1];
    const float* mu_s   = (const float*)d_in[2];
    const float* sg_s   = (const float*)d_in[3];
    const int*   tptr   = (const int*)d_in[4];
    float* out = (float*)d_out;

    float*    partials = (float*)d_ws;                                     // 8 MB
    _Float16* q16      = (_Float16*)((char*)d_ws + (size_t)NSPLIT * Q_TOTAL * 8 * 4);

    qbuild_k<<<Q_TOTAL / 256, 256, 0, stream>>>(x, q16);
    score_k<<<GRID, 256, 0, stream>>>(q16, images, mu_s, sg_s, tptr, partials);
    combine_k<<<Q_TOTAL / 256, 256, 0, stream>>>(
        x, partials, mu_s, sg_s, tptr, out);
}

// Round 6
// 113.430 us; speedup vs baseline: 2.5859x; 1.1076x over previous
//
#include <hip/hip_runtime.h>
#include <cstddef>

// Problem constants
#define P_TOTAL 32768            // keys (32 images x 32 x 32)
#define Q_TOTAL 4096             // queries (4 x 32 x 32)
#define NSPLIT 64                // key splits
#define KPS 512                  // keys per split
#define TILES 32                 // 16-key MFMA tiles per split
#define QPERWG 256               // queries per workgroup (4 waves x 64)
#define NQG (Q_TOTAL / QPERWG)   // 16 query groups
#define GRID (NSPLIT * NQG)      // 1024 workgroups

typedef _Float16 half8 __attribute__((ext_vector_type(8)));
typedef float floatx4 __attribute__((ext_vector_type(4)));

__device__ __forceinline__ float fexp2(float x) {
#if defined(__has_builtin) && __has_builtin(__builtin_amdgcn_exp2f)
    return __builtin_amdgcn_exp2f(x);
#else
    return exp2f(x);
#endif
}

// ---------------------------------------------------------------------------
// Kernel 1: q16[Q][32] f16 query rows (27 patch vals, 1.0 bias-mate, zeros).
// ---------------------------------------------------------------------------
__global__ __launch_bounds__(256) void qbuild_k(
    const float* __restrict__ x, _Float16* __restrict__ q16)
{
    int q = blockIdx.x * 256 + threadIdx.x;   // 0..4095
    int b = q >> 10, rem = q & 1023, h = rem >> 5, w = rem & 31;
    const float* xb = x + (size_t)b * 3072;
    _Float16 row[32];
    #pragma unroll
    for (int c = 0; c < 3; c++)
      #pragma unroll
      for (int di = 0; di < 3; di++)
        #pragma unroll
        for (int dj = 0; dj < 3; dj++)
            row[c * 9 + di * 3 + dj] =
                (_Float16)xb[c * 1024 + ((h + di + 31) & 31) * 32 + ((w + dj + 31) & 31)];
    row[27] = (_Float16)1.0f;
    row[28] = (_Float16)0.f; row[29] = (_Float16)0.f;
    row[30] = (_Float16)0.f; row[31] = (_Float16)0.f;
    _Float16* qp = q16 + (size_t)q * 32;
    #pragma unroll
    for (int u = 0; u < 4; u++) ((float4*)qp)[u] = ((float4*)row)[u];
}

// ---------------------------------------------------------------------------
// Kernel 2: fused key-build + flash scorer, KEYS-IN-A orientation.
// mfma(A=key tile, B=queries, C): D[m=key=quad*4+reg][n=query=lane&15].
// Each lane owns ONE query column and 4 key rows per tile -> softmax
// reduction over keys is per-lane; only a 2-step cross-quad butterfly
// at the end (40 swizzles/wave vs 320 in the old orientation).
// Pass 1: per-lane max (+2-step merge). Pass 2: exact -m folded into the
// MFMA C operand, per-lane accumulate of s and center-weighted sums.
// Keys in 32 KB LDS (64-B f16 rows, 16B-chunk XOR swizzle); centers in a
// separate 4 KB f16 array (4 keys = 32 contiguous B, phase-broadcast reads).
// ---------------------------------------------------------------------------
__global__ __launch_bounds__(256) void score_k(
    const _Float16* __restrict__ q16, const float* __restrict__ images,
    const float* __restrict__ mu_sched, const float* __restrict__ sigma_sched,
    const int* __restrict__ tptr, float* __restrict__ partials)
{
    __shared__ char lds[KPS * 64 + KPS * 8];   // keys 32768 B + ctr 4096 B
    _Float16* ctr16 = (_Float16*)(lds + KPS * 64);
    int tid = threadIdx.x;
    int split = blockIdx.x >> 4;     // 0..63
    int qg    = blockIdx.x & 15;     // 0..15

    int t = tptr[0];
    float mu = mu_sched[t], sg = sigma_sched[t];
    const float LOG2E = 1.4426950408889634f;
    float inv2s2 = 1.0f / (2.0f * sg * sg);
    float s1     = 2.0f * mu * inv2s2 * LOG2E;   // key value scale
    float bscale = -mu * mu * inv2s2 * LOG2E;    // pnorm bias scale

    // ---- Phase 1: build this split's 512 keys into LDS (2 per thread) ----
    #pragma unroll
    for (int kk = 0; kk < 2; kk++) {
        int r = tid + kk * 256;                  // LDS key row 0..511
        int p = split * KPS + r;                 // global key id
        int n = p >> 10, rem = p & 1023, i = rem >> 5, j = rem & 31;
        const float* img = images + (size_t)n * 3072;
        _Float16 hrow[32];
        float pnorm = 0.f, c0 = 0.f, c1 = 0.f, c2 = 0.f;
        #pragma unroll
        for (int c = 0; c < 3; c++)
          #pragma unroll
          for (int di = 0; di < 3; di++)
            #pragma unroll
            for (int dj = 0; dj < 3; dj++) {
                int ii = i + di - 1, jj = j + dj - 1;
                float val = 0.f;
                if (ii >= 0 && ii < 32 && jj >= 0 && jj < 32)
                    val = img[c * 1024 + ii * 32 + jj];
                hrow[c * 9 + di * 3 + dj] = (_Float16)(val * s1);
                pnorm = fmaf(val, val, pnorm);
                if (di == 1 && dj == 1) { if (c == 0) c0 = val; else if (c == 1) c1 = val; else c2 = val; }
            }
        hrow[27] = (_Float16)(pnorm * bscale);
        hrow[28] = (_Float16)0.f; hrow[29] = (_Float16)0.f;
        hrow[30] = (_Float16)0.f; hrow[31] = (_Float16)0.f;
        int sw = (r >> 1) & 3;                   // chunk XOR swizzle
        float4* src4 = (float4*)hrow;
        #pragma unroll
        for (int c = 0; c < 4; c++)
            *(float4*)(lds + r * 64 + ((c ^ sw) << 4)) = src4[c];
        _Float16 crow[4] = {(_Float16)c0, (_Float16)c1, (_Float16)c2, (_Float16)0.f};
        *(float2*)(ctr16 + (size_t)r * 4) = *(float2*)crow;
    }

    // ---- B-fragments: queries from q16 (global, L2-hot) ----
    int lane = tid & 63, wid = tid >> 6;
    int col  = lane & 15, quad = lane >> 4;
    int qbase = qg * QPERWG + wid * 64;

    half8 qf[4];
    #pragma unroll
    for (int f = 0; f < 4; f++)
        qf[f] = *(const half8*)(q16 + (size_t)(qbase + f * 16 + col) * 32 + quad * 8);
    __syncthreads();

    int swc = (col >> 1) & 3;
    const char* abase = lds + col * 64 + ((quad ^ swc) << 4);   // key row = col

    // ---- Pass 1: per-lane max over this lane's keys ----
    float mx[4] = {-3e38f, -3e38f, -3e38f, -3e38f};
    {
        #pragma unroll 4
        for (int tile = 0; tile < TILES; tile++) {
            half8 ak = *(const half8*)(abase + tile * 1024);
            #pragma unroll
            for (int f = 0; f < 4; f++) {
                floatx4 a = __builtin_amdgcn_mfma_f32_16x16x32_f16(
                    ak, qf[f], (floatx4){0.f, 0.f, 0.f, 0.f}, 0, 0, 0);
                mx[f] = fmaxf(mx[f], fmaxf(fmaxf(a[0], a[1]), fmaxf(a[2], a[3])));
            }
        }
    }
    // cross-quad max merge (lanes sharing col: xor 16, 32)
    #pragma unroll
    for (int f = 0; f < 4; f++) {
        mx[f] = fmaxf(mx[f], __shfl_xor(mx[f], 16, 64));
        mx[f] = fmaxf(mx[f], __shfl_xor(mx[f], 32, 64));
    }
    floatx4 nmv[4];
    #pragma unroll
    for (int f = 0; f < 4; f++)
        nmv[f] = (floatx4){-mx[f], -mx[f], -mx[f], -mx[f]};

    // ---- Pass 2: exp2 (exact -m in C operand) + per-lane accumulate ----
    float sv[4] = {0.f, 0.f, 0.f, 0.f};
    float w0[4] = {0.f, 0.f, 0.f, 0.f};
    float w1[4] = {0.f, 0.f, 0.f, 0.f};
    float w2[4] = {0.f, 0.f, 0.f, 0.f};
    {
        #pragma unroll 2
        for (int tile = 0; tile < TILES; tile++) {
            half8 ak = *(const half8*)(abase + tile * 1024);
            int gr = tile * 16 + quad * 4;       // this lane's 4 key rows
            half8 chA = *(const half8*)(ctr16 + (size_t)gr * 4);        // rows gr, gr+1
            half8 chB = *(const half8*)(ctr16 + (size_t)(gr + 2) * 4);  // rows gr+2, gr+3
            float c0v[4] = {(float)chA[0], (float)chA[4], (float)chB[0], (float)chB[4]};
            float c1v[4] = {(float)chA[1], (float)chA[5], (float)chB[1], (float)chB[5]};
            float c2v[4] = {(float)chA[2], (float)chA[6], (float)chB[2], (float)chB[6]};
            #pragma unroll
            for (int f = 0; f < 4; f++) {
                floatx4 a = __builtin_amdgcn_mfma_f32_16x16x32_f16(ak, qf[f], nmv[f], 0, 0, 0);
                #pragma unroll
                for (int r = 0; r < 4; r++) {
                    float e = fexp2(a[r]);
                    sv[f] += e;
                    w0[f] = fmaf(e, c0v[r], w0[f]);
                    w1[f] = fmaf(e, c1v[r], w1[f]);
                    w2[f] = fmaf(e, c2v[r], w2[f]);
                }
            }
        }
    }
    // cross-quad sum merge (all quads used the same m -> plain adds)
    #pragma unroll
    for (int f = 0; f < 4; f++) {
        sv[f] += __shfl_xor(sv[f], 16, 64);  sv[f] += __shfl_xor(sv[f], 32, 64);
        w0[f] += __shfl_xor(w0[f], 16, 64);  w0[f] += __shfl_xor(w0[f], 32, 64);
        w1[f] += __shfl_xor(w1[f], 16, 64);  w1[f] += __shfl_xor(w1[f], 32, 64);
        w2[f] += __shfl_xor(w2[f], 16, 64);  w2[f] += __shfl_xor(w2[f], 32, 64);
    }

    if (quad == 0) {
        #pragma unroll
        for (int f = 0; f < 4; f++) {
            int q = qbase + f * 16 + col;
            float* pp = partials + ((size_t)split * Q_TOTAL + q) * 8;
            *(float4*)pp = make_float4(mx[f], sv[f], w0[f], w1[f]);
            pp[4] = w2[f];
        }
    }
}

// ---------------------------------------------------------------------------
// Kernel 3: merge NSPLIT partials per query (online), write output.
// ---------------------------------------------------------------------------
__global__ __launch_bounds__(256) void combine_k(
    const float* __restrict__ x, const float* __restrict__ partials,
    const float* __restrict__ mu_sched, const float* __restrict__ sigma_sched,
    const int* __restrict__ tptr, float* __restrict__ out)
{
    int q = blockIdx.x * 256 + threadIdx.x;   // 0..4095
    int t = tptr[0];
    float mu = mu_sched[t], sg = sigma_sched[t];
    float inv_s2 = 1.0f / (sg * sg);

    float M = -3e38f, S = 0.f, W0 = 0.f, W1 = 0.f, W2 = 0.f;
    for (int sp = 0; sp < NSPLIT; sp++) {
        const float* pp = partials + ((size_t)sp * Q_TOTAL + q) * 8;
        float4 a = *(const float4*)pp;
        float w2v = pp[4];
        float mnew = fmaxf(M, a.x);
        float sco = fexp2(M - mnew);
        float scn = fexp2(a.x - mnew);
        S  = fmaf(S,  sco, a.y * scn);
        W0 = fmaf(W0, sco, a.z * scn);
        W1 = fmaf(W1, sco, a.w * scn);
        W2 = fmaf(W2, sco, w2v * scn);
        M = mnew;
    }
    float invS = 1.0f / S;
    int b = q >> 10, rem = q & 1023;
    #pragma unroll
    for (int c = 0; c < 3; c++) {
        float Wc = (c == 0) ? W0 : (c == 1 ? W1 : W2);
        float xc = x[(size_t)b * 3072 + c * 1024 + rem];
        out[(size_t)b * 3072 + c * 1024 + rem] = -(xc - mu * Wc * invS) * inv_s2;
    }
}

extern "C" void kernel_launch(void* const* d_in, const int* in_sizes, int n_in,
                              void* d_out, int out_size, void* d_ws, size_t ws_size,
                              hipStream_t stream) {
    const float* x      = (const float*)d_in[0];
    const float* images = (const float*)d_in[1];
    const float* mu_s   = (const float*)d_in[2];
    const float* sg_s   = (const float*)d_in[3];
    const int*   tptr   = (const int*)d_in[4];
    float* out = (float*)d_out;

    float*    partials = (float*)d_ws;                                     // 8 MB
    _Float16* q16      = (_Float16*)((char*)d_ws + (size_t)NSPLIT * Q_TOTAL * 8 * 4);

    qbuild_k<<<Q_TOTAL / 256, 256, 0, stream>>>(x, q16);
    score_k<<<GRID, 256, 0, stream>>>(q16, images, mu_s, sg_s, tptr, partials);
    combine_k<<<Q_TOTAL / 256, 256, 0, stream>>>(
        x, partials, mu_s, sg_s, tptr, out);
}